// Round 1
// baseline (985.424 us; speedup 1.0000x reference)
//
#include <hip/hip_runtime.h>

#define NN 100000
#define EE 1600000
#define DD 128
#define LL 3

typedef float f32x4 __attribute__((ext_vector_type(4)));
typedef _Float16 f16x8 __attribute__((ext_vector_type(8)));
typedef unsigned short u16;
typedef unsigned int u32;
typedef u16 u16x8 __attribute__((ext_vector_type(8)));

__device__ __forceinline__ u16 f2h_bits(float f) {
    _Float16 h = (_Float16)f;
    return __builtin_bit_cast(u16, h);
}

// ---------------- CSR build ----------------

__global__ void count_deg_kernel(const int* __restrict__ dst, int* __restrict__ deg) {
    int e = blockIdx.x * blockDim.x + threadIdx.x;
    if (e < EE) atomicAdd(&deg[dst[e]], 1);
}

__global__ void scan_kernel(const int* __restrict__ deg, int* __restrict__ row_ptr,
                            int* __restrict__ cursor) {
    __shared__ int part[1024];
    int t = threadIdx.x;
    const int per = (NN + 1023) / 1024;   // 98
    int s = t * per;
    int e = s + per; if (e > NN) e = NN;
    int sum = 0;
    if (s < NN) for (int i = s; i < e; ++i) sum += deg[i];
    part[t] = sum;
    __syncthreads();
    for (int off = 1; off < 1024; off <<= 1) {
        int v = (t >= off) ? part[t - off] : 0;
        __syncthreads();
        part[t] += v;
        __syncthreads();
    }
    int run = (t > 0) ? part[t - 1] : 0;
    if (s < NN) {
        for (int i = s; i < e; ++i) {
            row_ptr[i] = run; cursor[i] = run; run += deg[i];
        }
    }
    if (t == 1023) row_ptr[NN] = part[1023];
}

__global__ void fill_kernel(const int* __restrict__ src, const int* __restrict__ dst,
                            int* __restrict__ cursor, int* __restrict__ col) {
    int e = blockIdx.x * blockDim.x + threadIdx.x;
    if (e < EE) {
        int d = dst[e];
        int pos = atomicAdd(&cursor[d], 1);
        col[pos] = src[e];
    }
}

// ---------------- aggregation: z = h + sum_{j in N(i)} h[j] ----------------
// one wave (64 lanes, float2 each) per node

__global__ void agg_kernel(const float* __restrict__ h, const int* __restrict__ row_ptr,
                           const int* __restrict__ col, float* __restrict__ z) {
    int node = blockIdx.x * 4 + (threadIdx.x >> 6);
    int c = threadIdx.x & 63;
    const float2* h2 = (const float2*)h;
    float2 acc = h2[(size_t)node * 64 + c];
    int beg = row_ptr[node], end = row_ptr[node + 1];
    for (int j = beg; j < end; ++j) {
        int s = col[j];
        float2 v = h2[(size_t)s * 64 + c];
        acc.x += v.x; acc.y += v.y;
    }
    ((float2*)z)[(size_t)node * 64 + c] = acc;
}

// ---------------- fused MLP + LayerNorm + ReLU ----------------
// block = 256 threads = 4 waves; each wave owns 16 rows; M-tile = 64 rows.
// LDS: [0,32768)   W transposed (c-major) fp16, XOR-swizzled, W1 then W2 (phased)
//      [32768,49152) hidden transpose buffer, 64 rows x 128 cols fp16, swizzled

__device__ __forceinline__ void stage_w(const float* __restrict__ W, unsigned char* lds, int tid) {
    #pragma unroll
    for (int i = 0; i < 8; ++i) {
        int p = tid + i * 256;
        int c = p & 127;
        int k0 = (p >> 7) << 3;
        u16x8 t;
        #pragma unroll
        for (int j = 0; j < 8; ++j) t[j] = f2h_bits(W[(k0 + j) * 128 + c]);
        u32 off = ((((u32)c << 7) + k0) << 1) ^ (((u32)c & 7) << 4);
        *(u16x8*)(lds + off) = t;
    }
}

__global__ __launch_bounds__(256) void mlp_kernel(
    const float* __restrict__ z, const float* __restrict__ W1,
    const float* __restrict__ b1v, const float* __restrict__ W2,
    const float* __restrict__ b2v, const float* __restrict__ gam,
    const float* __restrict__ bet, float* __restrict__ hout)
{
    __shared__ __align__(16) unsigned char lds[49152];
    const int tid = threadIdx.x;
    const int lane = tid & 63;
    const int w = tid >> 6;       // wave 0..3
    const int rl = lane & 15;     // row (A) / col (B,D) within 16
    const int kg = lane >> 4;     // k-group 0..3
    const int tile = blockIdx.x * 64;
    const int r0 = tile + w * 16;

    stage_w(W1, lds, tid);

    // A-frags from z (fp32 -> fp16). rows r0+rl, clamped for the ragged tail.
    int zrow = r0 + rl; if (zrow > NN - 1) zrow = NN - 1;
    const float* zp = z + (size_t)zrow * 128;
    f16x8 afr[4];
    #pragma unroll
    for (int kt = 0; kt < 4; ++kt) {
        int kb = kt * 32 + kg * 8;
        float4 v0 = *(const float4*)(zp + kb);
        float4 v1 = *(const float4*)(zp + kb + 4);
        f16x8 a;
        a[0] = (_Float16)v0.x; a[1] = (_Float16)v0.y; a[2] = (_Float16)v0.z; a[3] = (_Float16)v0.w;
        a[4] = (_Float16)v1.x; a[5] = (_Float16)v1.y; a[6] = (_Float16)v1.z; a[7] = (_Float16)v1.w;
        afr[kt] = a;
    }
    __syncthreads();   // W1 staged

    // GEMM1 + bias + relu -> hidden transpose buffer (per-wave private rows)
    #pragma unroll
    for (int nt = 0; nt < 8; ++nt) {
        f32x4 acc = {0.f, 0.f, 0.f, 0.f};
        int c = nt * 16 + rl;
        #pragma unroll
        for (int kt = 0; kt < 4; ++kt) {
            int kb = kt * 32 + kg * 8;
            u32 off = ((((u32)c << 7) + kb) << 1) ^ (((u32)c & 7) << 4);
            f16x8 b = *(const f16x8*)(lds + off);
            acc = __builtin_amdgcn_mfma_f32_16x16x32_f16(afr[kt], b, acc, 0, 0, 0);
        }
        float bias = b1v[c];
        #pragma unroll
        for (int r = 0; r < 4; ++r) {
            float v = acc[r] + bias;
            v = v > 0.f ? v : 0.f;
            int fullrow = w * 16 + kg * 4 + r;       // 0..63
            u32 hoff = 32768u + (((((u32)fullrow << 7) + c) << 1) ^ (((u32)fullrow & 7) << 4));
            *(u16*)(lds + hoff) = f2h_bits(v);
        }
    }

    __syncthreads();   // all W1 reads done
    stage_w(W2, lds, tid);

    // A-frags for GEMM2 from hidden buffer (same-wave rows; compiler inserts lgkmcnt)
    f16x8 afr2[4];
    int hrow = w * 16 + rl;
    #pragma unroll
    for (int kt = 0; kt < 4; ++kt) {
        int kb = kt * 32 + kg * 8;
        u32 off = 32768u + (((((u32)hrow << 7) + kb) << 1) ^ (((u32)hrow & 7) << 4));
        afr2[kt] = *(const f16x8*)(lds + off);
    }
    __syncthreads();   // W2 staged

    // GEMM2 + bias
    f32x4 acc2[8];
    #pragma unroll
    for (int nt = 0; nt < 8; ++nt) {
        f32x4 acc = {0.f, 0.f, 0.f, 0.f};
        int c = nt * 16 + rl;
        #pragma unroll
        for (int kt = 0; kt < 4; ++kt) {
            int kb = kt * 32 + kg * 8;
            u32 off = ((((u32)c << 7) + kb) << 1) ^ (((u32)c & 7) << 4);
            f16x8 b = *(const f16x8*)(lds + off);
            acc = __builtin_amdgcn_mfma_f32_16x16x32_f16(afr2[kt], b, acc, 0, 0, 0);
        }
        float bias = b2v[c];
        acc[0] += bias; acc[1] += bias; acc[2] += bias; acc[3] += bias;
        acc2[nt] = acc;
    }

    // LayerNorm + ReLU + store. lane holds rows kg*4+r, cols nt*16+rl.
    float gamv[8], betv[8];
    #pragma unroll
    for (int nt = 0; nt < 8; ++nt) { gamv[nt] = gam[nt * 16 + rl]; betv[nt] = bet[nt * 16 + rl]; }
    #pragma unroll
    for (int r = 0; r < 4; ++r) {
        float s1 = 0.f, s2 = 0.f;
        #pragma unroll
        for (int nt = 0; nt < 8; ++nt) { float v = acc2[nt][r]; s1 += v; s2 += v * v; }
        #pragma unroll
        for (int m = 1; m < 16; m <<= 1) {
            s1 += __shfl_xor(s1, m, 64);
            s2 += __shfl_xor(s2, m, 64);
        }
        float mu = s1 * (1.f / 128.f);
        float var = s2 * (1.f / 128.f) - mu * mu;
        float rstd = rsqrtf(var + 1e-5f);
        int fullrow = r0 + kg * 4 + r;
        if (fullrow < NN) {
            float* op = hout + (size_t)fullrow * 128;
            #pragma unroll
            for (int nt = 0; nt < 8; ++nt) {
                float v = (acc2[nt][r] - mu) * rstd * gamv[nt] + betv[nt];
                v = v > 0.f ? v : 0.f;
                op[nt * 16 + rl] = v;
            }
        }
    }
}

// ---------------- host ----------------

extern "C" void kernel_launch(void* const* d_in, const int* in_sizes, int n_in,
                              void* d_out, int out_size, void* d_ws, size_t ws_size,
                              hipStream_t stream) {
    const float* x     = (const float*)d_in[0];
    const int*   ei    = (const int*)d_in[1];
    const float* W1    = (const float*)d_in[2];
    const float* b1    = (const float*)d_in[3];
    const float* W2    = (const float*)d_in[4];
    const float* b2    = (const float*)d_in[5];
    const float* gamma = (const float*)d_in[6];
    const float* beta  = (const float*)d_in[7];
    float* out = (float*)d_out;

    const int* src = ei;
    const int* dst = ei + EE;

    unsigned char* ws = (unsigned char*)d_ws;
    size_t off = 0;
    int* deg     = (int*)(ws + off); off += (size_t)NN * 4;
    int* cursor  = (int*)(ws + off); off += (size_t)NN * 4;
    int* row_ptr = (int*)(ws + off); off += (size_t)(NN + 1) * 4; off = (off + 255) & ~(size_t)255;
    int* colv    = (int*)(ws + off); off += (size_t)EE * 4;       off = (off + 255) & ~(size_t)255;
    float* zbuf  = (float*)(ws + off); off += (size_t)NN * DD * 4;
    float* hA    = (float*)(ws + off); off += (size_t)NN * DD * 4;

    hipMemsetAsync(deg, 0, (size_t)NN * 4, stream);
    count_deg_kernel<<<(EE + 255) / 256, 256, 0, stream>>>(dst, deg);
    scan_kernel<<<1, 1024, 0, stream>>>(deg, row_ptr, cursor);
    fill_kernel<<<(EE + 255) / 256, 256, 0, stream>>>(src, dst, cursor, colv);

    const float* hin = x;
    for (int l = 0; l < LL; ++l) {
        float* hout = (l == 0) ? hA : out;
        agg_kernel<<<NN / 4, 256, 0, stream>>>(hin, row_ptr, colv, zbuf);
        mlp_kernel<<<(NN + 63) / 64, 256, 0, stream>>>(
            zbuf, W1 + (size_t)l * DD * DD, b1 + l * DD,
            W2 + (size_t)l * DD * DD, b2 + l * DD,
            gamma + l * DD, beta + l * DD, hout);
        hin = hout;
    }
}

// Round 2
// 567.795 us; speedup vs baseline: 1.7355x; 1.7355x over previous
//
#include <hip/hip_runtime.h>

#define NN 100000
#define EE 1600000
#define DD 128
#define LL 3

typedef float f32x4 __attribute__((ext_vector_type(4)));
typedef _Float16 f16x8 __attribute__((ext_vector_type(8)));
typedef unsigned short u16;
typedef unsigned int u32;
typedef u16 u16x8 __attribute__((ext_vector_type(8)));

#define SCAN_CHUNK 1024
#define SCAN_NBLK ((NN + SCAN_CHUNK - 1) / SCAN_CHUNK)   // 98

__device__ __forceinline__ u16 f2h_bits(float f) {
    _Float16 h = (_Float16)f;
    return __builtin_bit_cast(u16, h);
}
__device__ __forceinline__ float2 h2f2(u32 v) {
    _Float16 lo = __builtin_bit_cast(_Float16, (u16)(v & 0xffff));
    _Float16 hi = __builtin_bit_cast(_Float16, (u16)(v >> 16));
    return make_float2((float)lo, (float)hi);
}
__device__ __forceinline__ u32 f22h(float x, float y) {
    return (u32)f2h_bits(x) | ((u32)f2h_bits(y) << 16);
}

// ---------------- CSR build ----------------

__global__ void count_deg_kernel(const int* __restrict__ dst, int* __restrict__ deg) {
    int e = blockIdx.x * blockDim.x + threadIdx.x;
    if (e < EE) atomicAdd(&deg[dst[e]], 1);
}

// partial sums: block b sums deg[b*1024 .. b*1024+1024)
__global__ void scan1_kernel(const int* __restrict__ deg, int* __restrict__ bsum) {
    __shared__ int red[256];
    int b = blockIdx.x, t = threadIdx.x;
    int base = b * SCAN_CHUNK + t * 4;
    int s = 0;
    #pragma unroll
    for (int i = 0; i < 4; ++i) { int idx = base + i; if (idx < NN) s += deg[idx]; }
    red[t] = s; __syncthreads();
    for (int off = 128; off > 0; off >>= 1) {
        if (t < off) red[t] += red[t + off];
        __syncthreads();
    }
    if (t == 0) bsum[b] = red[0];
}

// single-block exclusive scan of the 98 block sums
__global__ void scan2_kernel(const int* __restrict__ bsum, int* __restrict__ boff) {
    __shared__ int sh[128];
    int t = threadIdx.x;
    int v = (t < SCAN_NBLK) ? bsum[t] : 0;
    sh[t] = v; __syncthreads();
    for (int off = 1; off < 128; off <<= 1) {
        int u = (t >= off) ? sh[t - off] : 0;
        __syncthreads();
        sh[t] += u;
        __syncthreads();
    }
    if (t < SCAN_NBLK) boff[t] = sh[t] - v;
}

// per-block local exclusive scan + global offset -> row_ptr, cursor
__global__ void scan3_kernel(const int* __restrict__ deg, const int* __restrict__ boff,
                             int* __restrict__ row_ptr, int* __restrict__ cursor) {
    __shared__ int sh[256];
    int b = blockIdx.x, t = threadIdx.x;
    int base = b * SCAN_CHUNK + t * 4;
    int d[4]; int tot = 0;
    #pragma unroll
    for (int i = 0; i < 4; ++i) { int idx = base + i; d[i] = (idx < NN) ? deg[idx] : 0; tot += d[i]; }
    sh[t] = tot; __syncthreads();
    for (int off = 1; off < 256; off <<= 1) {
        int u = (t >= off) ? sh[t - off] : 0;
        __syncthreads();
        sh[t] += u;
        __syncthreads();
    }
    int run = boff[b] + sh[t] - tot;
    #pragma unroll
    for (int i = 0; i < 4; ++i) {
        int idx = base + i;
        if (idx < NN) { row_ptr[idx] = run; cursor[idx] = run; run += d[i]; }
    }
    if (b == 0 && t == 0) row_ptr[NN] = EE;
}

__global__ void fill_kernel(const int* __restrict__ src, const int* __restrict__ dst,
                            int* __restrict__ cursor, int* __restrict__ col) {
    int e = blockIdx.x * blockDim.x + threadIdx.x;
    if (e < EE) {
        int d = dst[e];
        int pos = atomicAdd(&cursor[d], 1);
        col[pos] = src[e];
    }
}

// ---------------- x (fp32) -> h16 ----------------

__global__ void cvt_kernel(const float* __restrict__ x, u32* __restrict__ h) {
    int i = blockIdx.x * blockDim.x + threadIdx.x;   // one float4 = 2 u32
    if (i < NN * 32) {
        float4 v = ((const float4*)x)[i];
        h[i * 2]     = f22h(v.x, v.y);
        h[i * 2 + 1] = f22h(v.z, v.w);
    }
}

// ---------------- aggregation: z16 = h16 + sum_{j in N(i)} h16[j] ----------------
// one wave per node; lane c holds halves [2c, 2c+1]; row = 64 u32 = 256B

__global__ void agg16_kernel(const u32* __restrict__ h, const int* __restrict__ row_ptr,
                             const int* __restrict__ col, u32* __restrict__ z) {
    int node = blockIdx.x * 4 + (threadIdx.x >> 6);
    int c = threadIdx.x & 63;
    float2 acc = h2f2(h[(size_t)node * 64 + c]);
    int beg = row_ptr[node], end = row_ptr[node + 1];
    int j = beg;
    for (; j + 2 <= end; j += 2) {
        int s0 = col[j], s1 = col[j + 1];
        u32 v0 = h[(size_t)s0 * 64 + c];
        u32 v1 = h[(size_t)s1 * 64 + c];
        float2 f0 = h2f2(v0), f1 = h2f2(v1);
        acc.x += f0.x; acc.y += f0.y;
        acc.x += f1.x; acc.y += f1.y;
    }
    if (j < end) {
        float2 f0 = h2f2(h[(size_t)col[j] * 64 + c]);
        acc.x += f0.x; acc.y += f0.y;
    }
    z[(size_t)node * 64 + c] = f22h(acc.x, acc.y);
}

// ---------------- fused MLP + LayerNorm + ReLU ----------------
// block = 256 threads = 4 waves; M-tile = 64 rows.
// LDS: [0,32768)   W transposed (c-major) fp16, XOR-swizzled, W1 then W2 (phased)
//      [32768,49152) hidden transpose buffer, 64 rows x 128 cols fp16, swizzled

__device__ __forceinline__ void stage_w(const float* __restrict__ W, unsigned char* lds, int tid) {
    #pragma unroll
    for (int i = 0; i < 8; ++i) {
        int p = tid + i * 256;
        int c = p & 127;
        int k0 = (p >> 7) << 3;
        u16x8 t;
        #pragma unroll
        for (int j = 0; j < 8; ++j) t[j] = f2h_bits(W[(k0 + j) * 128 + c]);
        u32 off = ((((u32)c << 7) + k0) << 1) ^ (((u32)c & 7) << 4);
        *(u16x8*)(lds + off) = t;
    }
}

__global__ __launch_bounds__(256) void mlp_kernel(
    const u16* __restrict__ z16, const float* __restrict__ W1,
    const float* __restrict__ b1v, const float* __restrict__ W2,
    const float* __restrict__ b2v, const float* __restrict__ gam,
    const float* __restrict__ bet, u16* __restrict__ h16out,
    float* __restrict__ f32out)
{
    __shared__ __align__(16) unsigned char lds[49152];
    const int tid = threadIdx.x;
    const int lane = tid & 63;
    const int w = tid >> 6;       // wave 0..3
    const int rl = lane & 15;     // row (A) / col (B,D) within 16
    const int kg = lane >> 4;     // k-group 0..3
    const int tile = blockIdx.x * 64;
    const int r0 = tile + w * 16;

    stage_w(W1, lds, tid);

    int zrow = r0 + rl; if (zrow > NN - 1) zrow = NN - 1;
    const u16* zp = z16 + (size_t)zrow * 128;
    f16x8 afr[4];
    #pragma unroll
    for (int kt = 0; kt < 4; ++kt)
        afr[kt] = *(const f16x8*)(zp + kt * 32 + kg * 8);
    __syncthreads();   // W1 staged

    // GEMM1 + bias + relu -> hidden transpose buffer
    #pragma unroll
    for (int nt = 0; nt < 8; ++nt) {
        f32x4 acc = {0.f, 0.f, 0.f, 0.f};
        int c = nt * 16 + rl;
        #pragma unroll
        for (int kt = 0; kt < 4; ++kt) {
            int kb = kt * 32 + kg * 8;
            u32 off = ((((u32)c << 7) + kb) << 1) ^ (((u32)c & 7) << 4);
            f16x8 b = *(const f16x8*)(lds + off);
            acc = __builtin_amdgcn_mfma_f32_16x16x32_f16(afr[kt], b, acc, 0, 0, 0);
        }
        float bias = b1v[c];
        #pragma unroll
        for (int r = 0; r < 4; ++r) {
            float v = acc[r] + bias;
            v = v > 0.f ? v : 0.f;
            int fullrow = w * 16 + kg * 4 + r;       // 0..63
            u32 hoff = 32768u + (((((u32)fullrow << 7) + c) << 1) ^ (((u32)fullrow & 7) << 4));
            *(u16*)(lds + hoff) = f2h_bits(v);
        }
    }

    __syncthreads();   // all W1 reads done
    stage_w(W2, lds, tid);

    f16x8 afr2[4];
    int hrow = w * 16 + rl;
    #pragma unroll
    for (int kt = 0; kt < 4; ++kt) {
        int kb = kt * 32 + kg * 8;
        u32 off = 32768u + (((((u32)hrow << 7) + kb) << 1) ^ (((u32)hrow & 7) << 4));
        afr2[kt] = *(const f16x8*)(lds + off);
    }
    __syncthreads();   // W2 staged

    // GEMM2 + bias
    f32x4 acc2[8];
    #pragma unroll
    for (int nt = 0; nt < 8; ++nt) {
        f32x4 acc = {0.f, 0.f, 0.f, 0.f};
        int c = nt * 16 + rl;
        #pragma unroll
        for (int kt = 0; kt < 4; ++kt) {
            int kb = kt * 32 + kg * 8;
            u32 off = ((((u32)c << 7) + kb) << 1) ^ (((u32)c & 7) << 4);
            f16x8 b = *(const f16x8*)(lds + off);
            acc = __builtin_amdgcn_mfma_f32_16x16x32_f16(afr2[kt], b, acc, 0, 0, 0);
        }
        float bias = b2v[c];
        acc[0] += bias; acc[1] += bias; acc[2] += bias; acc[3] += bias;
        acc2[nt] = acc;
    }

    // LayerNorm + ReLU + store. lane holds rows kg*4+r, cols nt*16+rl.
    float gamv[8], betv[8];
    #pragma unroll
    for (int nt = 0; nt < 8; ++nt) { gamv[nt] = gam[nt * 16 + rl]; betv[nt] = bet[nt * 16 + rl]; }
    #pragma unroll
    for (int r = 0; r < 4; ++r) {
        float s1 = 0.f, s2 = 0.f;
        #pragma unroll
        for (int nt = 0; nt < 8; ++nt) { float v = acc2[nt][r]; s1 += v; s2 += v * v; }
        #pragma unroll
        for (int m = 1; m < 16; m <<= 1) {
            s1 += __shfl_xor(s1, m, 64);
            s2 += __shfl_xor(s2, m, 64);
        }
        float mu = s1 * (1.f / 128.f);
        float var = s2 * (1.f / 128.f) - mu * mu;
        float rstd = rsqrtf(var + 1e-5f);
        int fullrow = r0 + kg * 4 + r;
        if (fullrow < NN) {
            #pragma unroll
            for (int nt = 0; nt < 8; ++nt) {
                float v = (acc2[nt][r] - mu) * rstd * gamv[nt] + betv[nt];
                v = v > 0.f ? v : 0.f;
                if (h16out) h16out[(size_t)fullrow * 128 + nt * 16 + rl] = f2h_bits(v);
                if (f32out) f32out[(size_t)fullrow * 128 + nt * 16 + rl] = v;
            }
        }
    }
}

// ---------------- host ----------------

extern "C" void kernel_launch(void* const* d_in, const int* in_sizes, int n_in,
                              void* d_out, int out_size, void* d_ws, size_t ws_size,
                              hipStream_t stream) {
    const float* x     = (const float*)d_in[0];
    const int*   ei    = (const int*)d_in[1];
    const float* W1    = (const float*)d_in[2];
    const float* b1    = (const float*)d_in[3];
    const float* W2    = (const float*)d_in[4];
    const float* b2    = (const float*)d_in[5];
    const float* gamma = (const float*)d_in[6];
    const float* beta  = (const float*)d_in[7];
    float* out = (float*)d_out;

    const int* src = ei;
    const int* dst = ei + EE;

    unsigned char* ws = (unsigned char*)d_ws;
    size_t off = 0;
    int* deg     = (int*)(ws + off); off += (size_t)NN * 4;
    int* cursor  = (int*)(ws + off); off += (size_t)NN * 4;
    int* row_ptr = (int*)(ws + off); off += (size_t)(NN + 1) * 4;
    int* bsum    = (int*)(ws + off); off += 128 * 4;
    int* boff    = (int*)(ws + off); off += 128 * 4; off = (off + 255) & ~(size_t)255;
    int* colv    = (int*)(ws + off); off += (size_t)EE * 4;       off = (off + 255) & ~(size_t)255;
    u32* h16a    = (u32*)(ws + off); off += (size_t)NN * 64 * 4;
    u32* h16b    = (u32*)(ws + off); off += (size_t)NN * 64 * 4;
    u32* z16     = (u32*)(ws + off); off += (size_t)NN * 64 * 4;

    hipMemsetAsync(deg, 0, (size_t)NN * 4, stream);
    count_deg_kernel<<<(EE + 255) / 256, 256, 0, stream>>>(dst, deg);
    scan1_kernel<<<SCAN_NBLK, 256, 0, stream>>>(deg, bsum);
    scan2_kernel<<<1, 128, 0, stream>>>(bsum, boff);
    scan3_kernel<<<SCAN_NBLK, 256, 0, stream>>>(deg, boff, row_ptr, cursor);
    fill_kernel<<<(EE + 255) / 256, 256, 0, stream>>>(src, dst, cursor, colv);
    cvt_kernel<<<(NN * 32 + 255) / 256, 256, 0, stream>>>(x, h16a);

    const u32* hin = h16a;
    u32* hnext = h16b;
    for (int l = 0; l < LL; ++l) {
        agg16_kernel<<<NN / 4, 256, 0, stream>>>(hin, row_ptr, colv, z16);
        mlp_kernel<<<(NN + 63) / 64, 256, 0, stream>>>(
            (const u16*)z16, W1 + (size_t)l * DD * DD, b1 + l * DD,
            W2 + (size_t)l * DD * DD, b2 + l * DD,
            gamma + l * DD, beta + l * DD,
            (l < LL - 1) ? (u16*)hnext : (u16*)nullptr,
            (l == LL - 1) ? out : (float*)nullptr);
        hin = hnext;
        hnext = (hnext == h16a) ? h16b : h16a;
    }
}

// Round 3
// 438.056 us; speedup vs baseline: 2.2495x; 1.2962x over previous
//
#include <hip/hip_runtime.h>

#define NN 100000
#define EE 1600000
#define DD 128
#define LL 3

typedef float f32x4 __attribute__((ext_vector_type(4)));
typedef _Float16 f16x8 __attribute__((ext_vector_type(8)));
typedef unsigned short u16;
typedef unsigned int u32;
typedef u16 u16x8 __attribute__((ext_vector_type(8)));

// CSR-build geometry: buckets of 256 nodes, chunks of 16384 edges
#define NBUCK ((NN + 255) / 256)          // 391
#define CHUNK 16384
#define NCHUNK ((EE + CHUNK - 1) / CHUNK) // 98

__device__ __forceinline__ u16 f2h_bits(float f) {
    _Float16 h = (_Float16)f;
    return __builtin_bit_cast(u16, h);
}
__device__ __forceinline__ float2 h2f2(u32 v) {
    _Float16 lo = __builtin_bit_cast(_Float16, (u16)(v & 0xffff));
    _Float16 hi = __builtin_bit_cast(_Float16, (u16)(v >> 16));
    return make_float2((float)lo, (float)hi);
}
__device__ __forceinline__ u32 f22h(float x, float y) {
    return (u32)f2h_bits(x) | ((u32)f2h_bits(y) << 16);
}

// ---------------- CSR build: bucketed counting sort by dst ----------------

// F1: per-chunk histogram over NBUCK buckets (bucket = dst >> 8)
__global__ __launch_bounds__(1024) void csr_hist(const int* __restrict__ dst,
                                                 int* __restrict__ hist_g) {
    __shared__ int h[NBUCK];
    int t = threadIdx.x, c = blockIdx.x;
    for (int i = t; i < NBUCK; i += 1024) h[i] = 0;
    __syncthreads();
    int base = c * CHUNK;
    #pragma unroll
    for (int i = 0; i < CHUNK / 1024; ++i) {
        int e = base + t + i * 1024;
        if (e < EE) atomicAdd(&h[dst[e] >> 8], 1);
    }
    __syncthreads();
    for (int i = t; i < NBUCK; i += 1024) hist_g[i * NCHUNK + c] = h[i];
}

// F2: turn [bucket][chunk] counts into global exclusive offsets; emit bucket bases
__global__ __launch_bounds__(512) void csr_scan(int* __restrict__ hist_g,
                                                int* __restrict__ bbase) {
    __shared__ int tot[512];
    int t = threadIdx.x;
    int sum = 0;
    if (t < NBUCK) {
        int* p = hist_g + t * NCHUNK;
        for (int c = 0; c < NCHUNK; ++c) { int v = p[c]; p[c] = sum; sum += v; }
    }
    tot[t] = sum; __syncthreads();
    for (int off = 1; off < 512; off <<= 1) {
        int u = (t >= off) ? tot[t - off] : 0;
        __syncthreads();
        tot[t] += u;
        __syncthreads();
    }
    int base = tot[t] - sum;   // exclusive
    if (t < NBUCK) {
        bbase[t] = base;
        int* p = hist_g + t * NCHUNK;
        for (int c = 0; c < NCHUNK; ++c) p[c] += base;
    }
    if (t == 0) bbase[NBUCK] = EE;
}

// F3: scatter packed records (src | dstlo<<17) into bucket-sorted order
__global__ __launch_bounds__(1024) void csr_scatter(const int* __restrict__ src,
                                                    const int* __restrict__ dst,
                                                    const int* __restrict__ hist_g,
                                                    u32* __restrict__ rec) {
    __shared__ int cur[NBUCK];
    int t = threadIdx.x, c = blockIdx.x;
    for (int i = t; i < NBUCK; i += 1024) cur[i] = hist_g[i * NCHUNK + c];
    __syncthreads();
    int base = c * CHUNK;
    #pragma unroll
    for (int i = 0; i < CHUNK / 1024; ++i) {
        int e = base + t + i * 1024;
        if (e < EE) {
            int d = dst[e];
            int slot = atomicAdd(&cur[d >> 8], 1);
            rec[slot] = (u32)src[e] | ((u32)(d & 255) << 17);
        }
    }
}

// F4: one block per bucket: local histogram+scan -> row_ptr, then place col[]
__global__ __launch_bounds__(256) void csr_finalize(const u32* __restrict__ rec,
                                                    const int* __restrict__ bbase,
                                                    int* __restrict__ row_ptr,
                                                    int* __restrict__ col) {
    __shared__ int cur[256];
    __shared__ int sc[256];
    int b = blockIdx.x, t = threadIdx.x;
    int base = bbase[b], tot = bbase[b + 1] - base;
    sc[t] = 0; __syncthreads();
    for (int r = t; r < tot; r += 256) atomicAdd(&sc[rec[base + r] >> 17], 1);
    __syncthreads();
    int v = sc[t];
    // inclusive scan -> exclusive
    for (int off = 1; off < 256; off <<= 1) {
        int u = (t >= off) ? sc[t - off] : 0;
        __syncthreads();
        sc[t] += u;
        __syncthreads();
    }
    int excl = sc[t] - v;
    cur[t] = excl;
    int nid = b * 256 + t;
    if (nid <= NN) row_ptr[nid] = base + excl;   // nid==NN lands on EE naturally
    __syncthreads();
    for (int r = t; r < tot; r += 256) {
        u32 rc = rec[base + r];
        int slot = atomicAdd(&cur[rc >> 17], 1);
        col[base + slot] = (int)(rc & 0x1FFFFu);
    }
}

// ---------------- x (fp32) -> h16 ----------------

__global__ void cvt_kernel(const float* __restrict__ x, u32* __restrict__ h) {
    int i = blockIdx.x * blockDim.x + threadIdx.x;   // one float4 = 2 u32
    if (i < NN * 32) {
        float4 v = ((const float4*)x)[i];
        h[i * 2]     = f22h(v.x, v.y);
        h[i * 2 + 1] = f22h(v.z, v.w);
    }
}

// ---------------- aggregation: z16 = h16 + sum_{j in N(i)} h16[j] ----------------

__global__ void agg16_kernel(const u32* __restrict__ h, const int* __restrict__ row_ptr,
                             const int* __restrict__ col, u32* __restrict__ z) {
    int node = blockIdx.x * 4 + (threadIdx.x >> 6);
    int c = threadIdx.x & 63;
    float2 acc = h2f2(h[(size_t)node * 64 + c]);
    int beg = row_ptr[node], end = row_ptr[node + 1];
    int j = beg;
    for (; j + 2 <= end; j += 2) {
        int s0 = col[j], s1 = col[j + 1];
        u32 v0 = h[(size_t)s0 * 64 + c];
        u32 v1 = h[(size_t)s1 * 64 + c];
        float2 f0 = h2f2(v0), f1 = h2f2(v1);
        acc.x += f0.x; acc.y += f0.y;
        acc.x += f1.x; acc.y += f1.y;
    }
    if (j < end) {
        float2 f0 = h2f2(h[(size_t)col[j] * 64 + c]);
        acc.x += f0.x; acc.y += f0.y;
    }
    z[(size_t)node * 64 + c] = f22h(acc.x, acc.y);
}

// ---------------- fused MLP + LayerNorm + ReLU ----------------
// block = 256 threads = 4 waves; M-tile = 64 rows.
// LDS: [0,32768)   W transposed (c-major) fp16, XOR-swizzled, W1 then W2 (phased)
//      [32768,49152) hidden transpose buffer, 64 rows x 128 cols fp16, swizzled

__device__ __forceinline__ void stage_w(const float* __restrict__ W, unsigned char* lds, int tid) {
    #pragma unroll
    for (int i = 0; i < 8; ++i) {
        int p = tid + i * 256;
        int c = p & 127;
        int k0 = (p >> 7) << 3;
        u16x8 t;
        #pragma unroll
        for (int j = 0; j < 8; ++j) t[j] = f2h_bits(W[(k0 + j) * 128 + c]);
        u32 off = ((((u32)c << 7) + k0) << 1) ^ (((u32)c & 7) << 4);
        *(u16x8*)(lds + off) = t;
    }
}

__global__ __launch_bounds__(256) void mlp_kernel(
    const u16* __restrict__ z16, const float* __restrict__ W1,
    const float* __restrict__ b1v, const float* __restrict__ W2,
    const float* __restrict__ b2v, const float* __restrict__ gam,
    const float* __restrict__ bet, u16* __restrict__ h16out,
    float* __restrict__ f32out)
{
    __shared__ __align__(16) unsigned char lds[49152];
    const int tid = threadIdx.x;
    const int lane = tid & 63;
    const int w = tid >> 6;       // wave 0..3
    const int rl = lane & 15;     // row (A) / col (B,D) within 16
    const int kg = lane >> 4;     // k-group 0..3
    const int tile = blockIdx.x * 64;
    const int r0 = tile + w * 16;

    stage_w(W1, lds, tid);

    int zrow = r0 + rl; if (zrow > NN - 1) zrow = NN - 1;
    const u16* zp = z16 + (size_t)zrow * 128;
    f16x8 afr[4];
    #pragma unroll
    for (int kt = 0; kt < 4; ++kt)
        afr[kt] = *(const f16x8*)(zp + kt * 32 + kg * 8);
    __syncthreads();   // W1 staged

    // GEMM1 + bias + relu -> hidden transpose buffer
    #pragma unroll
    for (int nt = 0; nt < 8; ++nt) {
        f32x4 acc = {0.f, 0.f, 0.f, 0.f};
        int c = nt * 16 + rl;
        #pragma unroll
        for (int kt = 0; kt < 4; ++kt) {
            int kb = kt * 32 + kg * 8;
            u32 off = ((((u32)c << 7) + kb) << 1) ^ (((u32)c & 7) << 4);
            f16x8 b = *(const f16x8*)(lds + off);
            acc = __builtin_amdgcn_mfma_f32_16x16x32_f16(afr[kt], b, acc, 0, 0, 0);
        }
        float bias = b1v[c];
        #pragma unroll
        for (int r = 0; r < 4; ++r) {
            float v = acc[r] + bias;
            v = v > 0.f ? v : 0.f;
            int fullrow = w * 16 + kg * 4 + r;       // 0..63
            u32 hoff = 32768u + (((((u32)fullrow << 7) + c) << 1) ^ (((u32)fullrow & 7) << 4));
            *(u16*)(lds + hoff) = f2h_bits(v);
        }
    }

    __syncthreads();   // all W1 reads done
    stage_w(W2, lds, tid);

    f16x8 afr2[4];
    int hrow = w * 16 + rl;
    #pragma unroll
    for (int kt = 0; kt < 4; ++kt) {
        int kb = kt * 32 + kg * 8;
        u32 off = 32768u + (((((u32)hrow << 7) + kb) << 1) ^ (((u32)hrow & 7) << 4));
        afr2[kt] = *(const f16x8*)(lds + off);
    }
    __syncthreads();   // W2 staged

    // GEMM2 + bias
    f32x4 acc2[8];
    #pragma unroll
    for (int nt = 0; nt < 8; ++nt) {
        f32x4 acc = {0.f, 0.f, 0.f, 0.f};
        int c = nt * 16 + rl;
        #pragma unroll
        for (int kt = 0; kt < 4; ++kt) {
            int kb = kt * 32 + kg * 8;
            u32 off = ((((u32)c << 7) + kb) << 1) ^ (((u32)c & 7) << 4);
            f16x8 b = *(const f16x8*)(lds + off);
            acc = __builtin_amdgcn_mfma_f32_16x16x32_f16(afr2[kt], b, acc, 0, 0, 0);
        }
        float bias = b2v[c];
        acc[0] += bias; acc[1] += bias; acc[2] += bias; acc[3] += bias;
        acc2[nt] = acc;
    }

    // LayerNorm + ReLU + store. lane holds rows kg*4+r, cols nt*16+rl.
    float gamv[8], betv[8];
    #pragma unroll
    for (int nt = 0; nt < 8; ++nt) { gamv[nt] = gam[nt * 16 + rl]; betv[nt] = bet[nt * 16 + rl]; }
    #pragma unroll
    for (int r = 0; r < 4; ++r) {
        float s1 = 0.f, s2 = 0.f;
        #pragma unroll
        for (int nt = 0; nt < 8; ++nt) { float v = acc2[nt][r]; s1 += v; s2 += v * v; }
        #pragma unroll
        for (int m = 1; m < 16; m <<= 1) {
            s1 += __shfl_xor(s1, m, 64);
            s2 += __shfl_xor(s2, m, 64);
        }
        float mu = s1 * (1.f / 128.f);
        float var = s2 * (1.f / 128.f) - mu * mu;
        float rstd = rsqrtf(var + 1e-5f);
        int fullrow = r0 + kg * 4 + r;
        if (fullrow < NN) {
            #pragma unroll
            for (int nt = 0; nt < 8; ++nt) {
                float v = (acc2[nt][r] - mu) * rstd * gamv[nt] + betv[nt];
                v = v > 0.f ? v : 0.f;
                if (h16out) h16out[(size_t)fullrow * 128 + nt * 16 + rl] = f2h_bits(v);
                if (f32out) f32out[(size_t)fullrow * 128 + nt * 16 + rl] = v;
            }
        }
    }
}

// ---------------- host ----------------

extern "C" void kernel_launch(void* const* d_in, const int* in_sizes, int n_in,
                              void* d_out, int out_size, void* d_ws, size_t ws_size,
                              hipStream_t stream) {
    const float* x     = (const float*)d_in[0];
    const int*   ei    = (const int*)d_in[1];
    const float* W1    = (const float*)d_in[2];
    const float* b1    = (const float*)d_in[3];
    const float* W2    = (const float*)d_in[4];
    const float* b2    = (const float*)d_in[5];
    const float* gamma = (const float*)d_in[6];
    const float* beta  = (const float*)d_in[7];
    float* out = (float*)d_out;

    const int* src = ei;
    const int* dst = ei + EE;

    unsigned char* ws = (unsigned char*)d_ws;
    size_t off = 0;
    int* hist_g  = (int*)(ws + off); off += (size_t)NBUCK * NCHUNK * 4;
    int* bbase   = (int*)(ws + off); off += (size_t)(NBUCK + 1) * 4;
    int* row_ptr = (int*)(ws + off); off += (size_t)(NN + 1) * 4; off = (off + 255) & ~(size_t)255;
    u32* rec     = (u32*)(ws + off); off += (size_t)EE * 4;       off = (off + 255) & ~(size_t)255;
    int* colv    = (int*)(ws + off); off += (size_t)EE * 4;       off = (off + 255) & ~(size_t)255;
    u32* h16a    = (u32*)(ws + off); off += (size_t)NN * 64 * 4;
    u32* h16b    = (u32*)(ws + off); off += (size_t)NN * 64 * 4;
    u32* z16     = (u32*)(ws + off); off += (size_t)NN * 64 * 4;

    csr_hist<<<NCHUNK, 1024, 0, stream>>>(dst, hist_g);
    csr_scan<<<1, 512, 0, stream>>>(hist_g, bbase);
    csr_scatter<<<NCHUNK, 1024, 0, stream>>>(src, dst, hist_g, rec);
    csr_finalize<<<NBUCK, 256, 0, stream>>>(rec, bbase, row_ptr, colv);
    cvt_kernel<<<(NN * 32 + 255) / 256, 256, 0, stream>>>(x, h16a);

    const u32* hin = h16a;
    u32* hnext = h16b;
    for (int l = 0; l < LL; ++l) {
        agg16_kernel<<<NN / 4, 256, 0, stream>>>(hin, row_ptr, colv, z16);
        mlp_kernel<<<(NN + 63) / 64, 256, 0, stream>>>(
            (const u16*)z16, W1 + (size_t)l * DD * DD, b1 + l * DD,
            W2 + (size_t)l * DD * DD, b2 + l * DD,
            gamma + l * DD, beta + l * DD,
            (l < LL - 1) ? (u16*)hnext : (u16*)nullptr,
            (l == LL - 1) ? out : (float*)nullptr);
        hin = hnext;
        hnext = (hnext == h16a) ? h16b : h16a;
    }
}

// Round 4
// 356.366 us; speedup vs baseline: 2.7652x; 1.2292x over previous
//
#include <hip/hip_runtime.h>

#define NN 100000
#define EE 1600000
#define DD 128
#define LL 3

typedef float f32x4 __attribute__((ext_vector_type(4)));
typedef _Float16 f16x8 __attribute__((ext_vector_type(8)));
typedef unsigned short u16;
typedef unsigned int u32;
typedef u16 u16x8 __attribute__((ext_vector_type(8)));

// CSR-build geometry: buckets of 256 nodes, chunks of 16384 edges
#define NBUCK ((NN + 255) / 256)          // 391
#define CHUNK 16384
#define NCHUNK ((EE + CHUNK - 1) / CHUNK) // 98

__device__ __forceinline__ u16 f2h_bits(float f) {
    _Float16 h = (_Float16)f;
    return __builtin_bit_cast(u16, h);
}
__device__ __forceinline__ float2 h2f2(u32 v) {
    _Float16 lo = __builtin_bit_cast(_Float16, (u16)(v & 0xffff));
    _Float16 hi = __builtin_bit_cast(_Float16, (u16)(v >> 16));
    return make_float2((float)lo, (float)hi);
}
__device__ __forceinline__ u32 f22h(float x, float y) {
    return (u32)f2h_bits(x) | ((u32)f2h_bits(y) << 16);
}

// ---------------- CSR build: bucketed counting sort by dst ----------------

__global__ __launch_bounds__(1024) void csr_hist(const int* __restrict__ dst,
                                                 int* __restrict__ hist_g) {
    __shared__ int h[NBUCK];
    int t = threadIdx.x, c = blockIdx.x;
    for (int i = t; i < NBUCK; i += 1024) h[i] = 0;
    __syncthreads();
    int base = c * CHUNK;
    #pragma unroll
    for (int i = 0; i < CHUNK / 1024; ++i) {
        int e = base + t + i * 1024;
        if (e < EE) atomicAdd(&h[dst[e] >> 8], 1);
    }
    __syncthreads();
    for (int i = t; i < NBUCK; i += 1024) hist_g[i * NCHUNK + c] = h[i];
}

__global__ __launch_bounds__(512) void csr_scan(int* __restrict__ hist_g,
                                                int* __restrict__ bbase) {
    __shared__ int tot[512];
    int t = threadIdx.x;
    int sum = 0;
    if (t < NBUCK) {
        int* p = hist_g + t * NCHUNK;
        for (int c = 0; c < NCHUNK; ++c) { int v = p[c]; p[c] = sum; sum += v; }
    }
    tot[t] = sum; __syncthreads();
    for (int off = 1; off < 512; off <<= 1) {
        int u = (t >= off) ? tot[t - off] : 0;
        __syncthreads();
        tot[t] += u;
        __syncthreads();
    }
    int base = tot[t] - sum;   // exclusive
    if (t < NBUCK) {
        bbase[t] = base;
        int* p = hist_g + t * NCHUNK;
        for (int c = 0; c < NCHUNK; ++c) p[c] += base;
    }
    if (t == 0) bbase[NBUCK] = EE;
}

__global__ __launch_bounds__(1024) void csr_scatter(const int* __restrict__ src,
                                                    const int* __restrict__ dst,
                                                    const int* __restrict__ hist_g,
                                                    u32* __restrict__ rec) {
    __shared__ int cur[NBUCK];
    int t = threadIdx.x, c = blockIdx.x;
    for (int i = t; i < NBUCK; i += 1024) cur[i] = hist_g[i * NCHUNK + c];
    __syncthreads();
    int base = c * CHUNK;
    #pragma unroll
    for (int i = 0; i < CHUNK / 1024; ++i) {
        int e = base + t + i * 1024;
        if (e < EE) {
            int d = dst[e];
            int slot = atomicAdd(&cur[d >> 8], 1);
            rec[slot] = (u32)src[e] | ((u32)(d & 255) << 17);
        }
    }
}

__global__ __launch_bounds__(256) void csr_finalize(const u32* __restrict__ rec,
                                                    const int* __restrict__ bbase,
                                                    int* __restrict__ row_ptr,
                                                    int* __restrict__ col) {
    __shared__ int cur[256];
    __shared__ int sc[256];
    int b = blockIdx.x, t = threadIdx.x;
    int base = bbase[b], tot = bbase[b + 1] - base;
    sc[t] = 0; __syncthreads();
    for (int r = t; r < tot; r += 256) atomicAdd(&sc[rec[base + r] >> 17], 1);
    __syncthreads();
    int v = sc[t];
    for (int off = 1; off < 256; off <<= 1) {
        int u = (t >= off) ? sc[t - off] : 0;
        __syncthreads();
        sc[t] += u;
        __syncthreads();
    }
    int excl = sc[t] - v;
    cur[t] = excl;
    int nid = b * 256 + t;
    if (nid <= NN) row_ptr[nid] = base + excl;
    __syncthreads();
    for (int r = t; r < tot; r += 256) {
        u32 rc = rec[base + r];
        int slot = atomicAdd(&cur[rc >> 17], 1);
        col[base + slot] = (int)(rc & 0x1FFFFu);
    }
}

// ---------------- x (fp32) -> h16 ----------------

__global__ void cvt_kernel(const float* __restrict__ x, u32* __restrict__ h) {
    int i = blockIdx.x * blockDim.x + threadIdx.x;
    if (i < NN * 32) {
        float4 v = ((const float4*)x)[i];
        h[i * 2]     = f22h(v.x, v.y);
        h[i * 2 + 1] = f22h(v.z, v.w);
    }
}

// ---------------- aggregation: z16 = h16 + sum_{j in N(i)} h16[j] ----------------
// one wave per node; lane c holds halves [2c,2c+1]; 8 gathers in flight per iter

__global__ __launch_bounds__(256) void agg16_kernel(
    const u32* __restrict__ h, const int* __restrict__ row_ptr,
    const int* __restrict__ col, u32* __restrict__ z) {
    int node = blockIdx.x * 4 + (threadIdx.x >> 6);
    int c = threadIdx.x & 63;
    const u32* hp = h + c;
    float2 acc = h2f2(hp[(size_t)node * 64]);
    int beg = row_ptr[node], end = row_ptr[node + 1];
    for (int j = beg; j < end; j += 8) {
        int n = end - j;                   // wave-uniform remaining count
        u32 v[8];
        #pragma unroll
        for (int q = 0; q < 8; ++q) {
            int jj = (q < n) ? j + q : j;  // pad with dup (L1 hit), no OOB
            v[q] = hp[(size_t)col[jj] * 64];
        }
        #pragma unroll
        for (int q = 0; q < 8; ++q) {
            if (q < n) { float2 f = h2f2(v[q]); acc.x += f.x; acc.y += f.y; }
        }
    }
    z[(size_t)node * 64 + c] = f22h(acc.x, acc.y);
}

// ---------------- fused MLP + LayerNorm + ReLU ----------------

__device__ __forceinline__ void stage_w(const float* __restrict__ W, unsigned char* lds, int tid) {
    #pragma unroll
    for (int i = 0; i < 8; ++i) {
        int p = tid + i * 256;
        int c = p & 127;
        int k0 = (p >> 7) << 3;
        u16x8 t;
        #pragma unroll
        for (int j = 0; j < 8; ++j) t[j] = f2h_bits(W[(k0 + j) * 128 + c]);
        u32 off = ((((u32)c << 7) + k0) << 1) ^ (((u32)c & 7) << 4);
        *(u16x8*)(lds + off) = t;
    }
}

__global__ __launch_bounds__(256) void mlp_kernel(
    const u16* __restrict__ z16, const float* __restrict__ W1,
    const float* __restrict__ b1v, const float* __restrict__ W2,
    const float* __restrict__ b2v, const float* __restrict__ gam,
    const float* __restrict__ bet, u16* __restrict__ h16out,
    float* __restrict__ f32out)
{
    __shared__ __align__(16) unsigned char lds[49152];
    const int tid = threadIdx.x;
    const int lane = tid & 63;
    const int w = tid >> 6;
    const int rl = lane & 15;
    const int kg = lane >> 4;
    const int tile = blockIdx.x * 64;
    const int r0 = tile + w * 16;

    stage_w(W1, lds, tid);

    int zrow = r0 + rl; if (zrow > NN - 1) zrow = NN - 1;
    const u16* zp = z16 + (size_t)zrow * 128;
    f16x8 afr[4];
    #pragma unroll
    for (int kt = 0; kt < 4; ++kt)
        afr[kt] = *(const f16x8*)(zp + kt * 32 + kg * 8);
    __syncthreads();   // W1 staged

    #pragma unroll
    for (int nt = 0; nt < 8; ++nt) {
        f32x4 acc = {0.f, 0.f, 0.f, 0.f};
        int c = nt * 16 + rl;
        #pragma unroll
        for (int kt = 0; kt < 4; ++kt) {
            int kb = kt * 32 + kg * 8;
            u32 off = ((((u32)c << 7) + kb) << 1) ^ (((u32)c & 7) << 4);
            f16x8 b = *(const f16x8*)(lds + off);
            acc = __builtin_amdgcn_mfma_f32_16x16x32_f16(afr[kt], b, acc, 0, 0, 0);
        }
        float bias = b1v[c];
        #pragma unroll
        for (int r = 0; r < 4; ++r) {
            float v = acc[r] + bias;
            v = v > 0.f ? v : 0.f;
            int fullrow = w * 16 + kg * 4 + r;
            u32 hoff = 32768u + (((((u32)fullrow << 7) + c) << 1) ^ (((u32)fullrow & 7) << 4));
            *(u16*)(lds + hoff) = f2h_bits(v);
        }
    }

    __syncthreads();
    stage_w(W2, lds, tid);

    f16x8 afr2[4];
    int hrow = w * 16 + rl;
    #pragma unroll
    for (int kt = 0; kt < 4; ++kt) {
        int kb = kt * 32 + kg * 8;
        u32 off = 32768u + (((((u32)hrow << 7) + kb) << 1) ^ (((u32)hrow & 7) << 4));
        afr2[kt] = *(const f16x8*)(lds + off);
    }
    __syncthreads();

    f32x4 acc2[8];
    #pragma unroll
    for (int nt = 0; nt < 8; ++nt) {
        f32x4 acc = {0.f, 0.f, 0.f, 0.f};
        int c = nt * 16 + rl;
        #pragma unroll
        for (int kt = 0; kt < 4; ++kt) {
            int kb = kt * 32 + kg * 8;
            u32 off = ((((u32)c << 7) + kb) << 1) ^ (((u32)c & 7) << 4);
            f16x8 b = *(const f16x8*)(lds + off);
            acc = __builtin_amdgcn_mfma_f32_16x16x32_f16(afr2[kt], b, acc, 0, 0, 0);
        }
        float bias = b2v[c];
        acc[0] += bias; acc[1] += bias; acc[2] += bias; acc[3] += bias;
        acc2[nt] = acc;
    }

    float gamv[8], betv[8];
    #pragma unroll
    for (int nt = 0; nt < 8; ++nt) { gamv[nt] = gam[nt * 16 + rl]; betv[nt] = bet[nt * 16 + rl]; }
    #pragma unroll
    for (int r = 0; r < 4; ++r) {
        float s1 = 0.f, s2 = 0.f;
        #pragma unroll
        for (int nt = 0; nt < 8; ++nt) { float v = acc2[nt][r]; s1 += v; s2 += v * v; }
        #pragma unroll
        for (int m = 1; m < 16; m <<= 1) {
            s1 += __shfl_xor(s1, m, 64);
            s2 += __shfl_xor(s2, m, 64);
        }
        float mu = s1 * (1.f / 128.f);
        float var = s2 * (1.f / 128.f) - mu * mu;
        float rstd = rsqrtf(var + 1e-5f);
        int fullrow = r0 + kg * 4 + r;
        if (fullrow < NN) {
            #pragma unroll
            for (int nt = 0; nt < 8; ++nt) {
                float v = (acc2[nt][r] - mu) * rstd * gamv[nt] + betv[nt];
                v = v > 0.f ? v : 0.f;
                if (h16out) h16out[(size_t)fullrow * 128 + nt * 16 + rl] = f2h_bits(v);
                if (f32out) f32out[(size_t)fullrow * 128 + nt * 16 + rl] = v;
            }
        }
    }
}

// ---------------- host ----------------

extern "C" void kernel_launch(void* const* d_in, const int* in_sizes, int n_in,
                              void* d_out, int out_size, void* d_ws, size_t ws_size,
                              hipStream_t stream) {
    const float* x     = (const float*)d_in[0];
    const int*   ei    = (const int*)d_in[1];
    const float* W1    = (const float*)d_in[2];
    const float* b1    = (const float*)d_in[3];
    const float* W2    = (const float*)d_in[4];
    const float* b2    = (const float*)d_in[5];
    const float* gamma = (const float*)d_in[6];
    const float* beta  = (const float*)d_in[7];
    float* out = (float*)d_out;

    const int* src = ei;
    const int* dst = ei + EE;

    unsigned char* ws = (unsigned char*)d_ws;
    size_t off = 0;
    int* hist_g  = (int*)(ws + off); off += (size_t)NBUCK * NCHUNK * 4;
    int* bbase   = (int*)(ws + off); off += (size_t)(NBUCK + 1) * 4;
    int* row_ptr = (int*)(ws + off); off += (size_t)(NN + 1) * 4; off = (off + 255) & ~(size_t)255;
    u32* rec     = (u32*)(ws + off); off += (size_t)EE * 4;       off = (off + 255) & ~(size_t)255;
    int* colv    = (int*)(ws + off); off += (size_t)EE * 4;       off = (off + 255) & ~(size_t)255;
    u32* h16a    = (u32*)(ws + off); off += (size_t)NN * 64 * 4;
    u32* h16b    = (u32*)(ws + off); off += (size_t)NN * 64 * 4;
    u32* z16     = (u32*)(ws + off); off += (size_t)NN * 64 * 4;

    csr_hist<<<NCHUNK, 1024, 0, stream>>>(dst, hist_g);
    csr_scan<<<1, 512, 0, stream>>>(hist_g, bbase);
    csr_scatter<<<NCHUNK, 1024, 0, stream>>>(src, dst, hist_g, rec);
    csr_finalize<<<NBUCK, 256, 0, stream>>>(rec, bbase, row_ptr, colv);
    cvt_kernel<<<(NN * 32 + 255) / 256, 256, 0, stream>>>(x, h16a);

    const u32* hin = h16a;
    u32* hnext = h16b;
    for (int l = 0; l < LL; ++l) {
        agg16_kernel<<<NN / 4, 256, 0, stream>>>(hin, row_ptr, colv, z16);
        mlp_kernel<<<(NN + 63) / 64, 256, 0, stream>>>(
            (const u16*)z16, W1 + (size_t)l * DD * DD, b1 + l * DD,
            W2 + (size_t)l * DD * DD, b2 + l * DD,
            gamma + l * DD, beta + l * DD,
            (l < LL - 1) ? (u16*)hnext : (u16*)nullptr,
            (l == LL - 1) ? out : (float*)nullptr);
        hin = hnext;
        hnext = (hnext == h16a) ? h16b : h16a;
    }
}